// Round 1
// baseline (303.585 us; speedup 1.0000x reference)
//
#include <hip/hip_runtime.h>
#include <hip/hip_bf16.h>
#include <math.h>

#define N_NODES 50000
#define N_EDGES 800000
#define IN_DIM 128
#define OUT_DIM 64
#define NEG_SLOPE 0.01f

// Kernel 1: z = h @ fc_w.T  (per-wave: one node, lane = out dim)
// Also computes s_src[n] = z[n]·a_src, s_dst[n] = z[n]·a_dst via wave reduce.
__global__ __launch_bounds__(256) void gemm_scores_kernel(
    const float* __restrict__ h, const float* __restrict__ fc_w,
    const float* __restrict__ attn_w,
    float* __restrict__ z, float* __restrict__ s_src, float* __restrict__ s_dst)
{
    __shared__ float wT[IN_DIM][OUT_DIM];   // 32 KB, transposed fc_w
    __shared__ float hrow[4][IN_DIM];       // 2 KB
    const int tid  = threadIdx.x;
    const int wave = tid >> 6;
    const int lane = tid & 63;
    const int n0   = blockIdx.x * 4;

    // stage fc_w transposed: fc_w[d][k] -> wT[k][d]
    for (int idx = tid; idx < IN_DIM * OUT_DIM; idx += 256) {
        int d = idx >> 7;          // / IN_DIM
        int k = idx & (IN_DIM - 1);
        wT[k][d] = fc_w[idx];
    }
    // stage 4 h rows
    for (int idx = tid; idx < 4 * IN_DIM; idx += 256) {
        int r = idx >> 7;
        int k = idx & (IN_DIM - 1);
        int n = n0 + r;
        hrow[r][k] = (n < N_NODES) ? h[n * IN_DIM + k] : 0.f;
    }
    __syncthreads();

    const int n = n0 + wave;
    if (n >= N_NODES) return;

    float acc = 0.f;
#pragma unroll
    for (int k = 0; k < IN_DIM; ++k)
        acc = fmaf(hrow[wave][k], wT[k][lane], acc);  // hrow broadcast; wT 2-way (free)

    z[n * OUT_DIM + lane] = acc;

    // per-node attention scores
    float ps = acc * attn_w[lane];
    float pd = acc * attn_w[OUT_DIM + lane];
#pragma unroll
    for (int off = 32; off; off >>= 1) {
        ps += __shfl_down(ps, off);
        pd += __shfl_down(pd, off);
    }
    if (lane == 0) { s_src[n] = ps; s_dst[n] = pd; }
}

// Kernel 2: row_ptr[n] = lower_bound(dst, n)  (dst is sorted)
__global__ __launch_bounds__(256) void row_ptr_kernel(
    const int* __restrict__ dst, int* __restrict__ row_ptr)
{
    int n = blockIdx.x * blockDim.x + threadIdx.x;
    if (n > N_NODES) return;
    int lo = 0, hi = N_EDGES;
    while (lo < hi) {
        int mid = (lo + hi) >> 1;
        if (dst[mid] < n) lo = mid + 1; else hi = mid;
    }
    row_ptr[n] = lo;
}

// Kernel 3: one wave per dst node; lane = output dim. Online softmax over the
// node's contiguous edge segment, gathering z[src] coalesced (64 lanes x 4B).
__global__ __launch_bounds__(256) void aggregate_kernel(
    const int* __restrict__ src, const int* __restrict__ row_ptr,
    const float* __restrict__ z, const float* __restrict__ s_src,
    const float* __restrict__ s_dst, float* __restrict__ out)
{
    const int tid  = threadIdx.x;
    const int wave = tid >> 6;
    const int lane = tid & 63;
    const int n = blockIdx.x * 4 + wave;
    if (n >= N_NODES) return;

    const int e0 = row_ptr[n];
    const int e1 = row_ptr[n + 1];

    float m = -INFINITY;   // running max
    float denom = 0.f;     // running sum of exp
    float acc = 0.f;       // running weighted sum (this lane's dim)
    const float sdn = s_dst[n];

    for (int e = e0; e < e1; ++e) {
        const int s = src[e];                    // broadcast load
        float ev = s_src[s] + sdn;               // broadcast load
        ev = (ev > 0.f) ? ev : ev * NEG_SLOPE;   // leaky_relu
        const float mn   = fmaxf(m, ev);
        const float corr = __expf(m - mn);       // exp(-inf)=0 on first edge
        const float p    = __expf(ev - mn);
        acc   = acc * corr + p * z[s * OUT_DIM + lane];
        denom = denom * corr + p;
        m = mn;
    }
    out[n * OUT_DIM + lane] = (denom > 0.f) ? (acc / denom) : 0.f;
}

extern "C" void kernel_launch(void* const* d_in, const int* in_sizes, int n_in,
                              void* d_out, int out_size, void* d_ws, size_t ws_size,
                              hipStream_t stream)
{
    const float* h      = (const float*)d_in[0];
    const int*   src    = (const int*)  d_in[1];
    const int*   dst    = (const int*)  d_in[2];
    const float* fc_w   = (const float*)d_in[3];
    const float* attn_w = (const float*)d_in[4];
    float*       out    = (float*)d_out;

    // workspace carve-out (all 256B-aligned)
    char* ws = (char*)d_ws;
    float* z      = (float*)ws;                                  // 50000*64*4 = 12.8 MB
    ws += ((size_t)N_NODES * OUT_DIM * sizeof(float) + 255) & ~(size_t)255;
    float* s_src  = (float*)ws;                                  // 200 KB
    ws += ((size_t)N_NODES * sizeof(float) + 255) & ~(size_t)255;
    float* s_dst  = (float*)ws;                                  // 200 KB
    ws += ((size_t)N_NODES * sizeof(float) + 255) & ~(size_t)255;
    int* row_ptr  = (int*)ws;                                    // 50001*4
    (void)ws_size;

    const int nodes_per_block = 4;
    const int nblocks = (N_NODES + nodes_per_block - 1) / nodes_per_block;  // 12500

    gemm_scores_kernel<<<nblocks, 256, 0, stream>>>(h, fc_w, attn_w, z, s_src, s_dst);
    row_ptr_kernel<<<(N_NODES + 1 + 255) / 256, 256, 0, stream>>>(dst, row_ptr);
    aggregate_kernel<<<nblocks, 256, 0, stream>>>(src, row_ptr, z, s_src, s_dst, out);
}